// Round 1
// baseline (436.525 us; speedup 1.0000x reference)
//
#include <hip/hip_runtime.h>

// BiGNN fused kernel (fp32 vector version).
// Stages: grouper1 (gather+MLP32->64+BN+ReLU+maxpool), grouper2 (C=64), concat, final 192->64 linear+BN+ReLU.
// Block = 256 threads = 64 rows x 4 waves; wave q owns output channels [16q,16q+16); lane = row.

constexpr int N_ROWS = 50000;
constexpr int KNBR   = 16;
constexpr int C1 = 32, C2 = 64, CL = 64, CG = 64;
constexpr float EPS = 1e-3f;
constexpr int ROWS_PER_BLOCK = 64;

template<int C>
__device__ __forceinline__ void grouper_chunk(
    const float* __restrict__ feat,   // [M, C]
    const int*   __restrict__ idx,    // [N, K]
    const float* __restrict__ W,      // [C, CG]
    const float* __restrict__ bnp,    // [4, CG]
    int row, int q, float* __restrict__ out16)
{
    float hmax[16], hmin[16];
#pragma unroll
    for (int d = 0; d < 16; ++d) { hmax[d] = -3.0e38f; hmin[d] = 3.0e38f; }

    // preload the 16 neighbor indices (int4-vectorized)
    int nb[KNBR];
    const int4* ip = reinterpret_cast<const int4*>(idx + (size_t)row * KNBR);
#pragma unroll
    for (int k4 = 0; k4 < KNBR / 4; ++k4) {
        int4 v = ip[k4];
        nb[4*k4+0] = v.x; nb[4*k4+1] = v.y; nb[4*k4+2] = v.z; nb[4*k4+3] = v.w;
    }

#pragma unroll 1   // keep code size in I$; inner body is already C*16 FMAs
    for (int k = 0; k < KNBR; ++k) {
        const float4* gp = reinterpret_cast<const float4*>(feat + (size_t)nb[k] * C);
        float g[C];
#pragma unroll
        for (int c4 = 0; c4 < C / 4; ++c4) {
            float4 v = gp[c4];
            g[4*c4+0] = v.x; g[4*c4+1] = v.y; g[4*c4+2] = v.z; g[4*c4+3] = v.w;
        }
        float h[16];
#pragma unroll
        for (int d = 0; d < 16; ++d) h[d] = 0.f;
#pragma unroll
        for (int c = 0; c < C; ++c) {
#pragma unroll
            for (int d = 0; d < 16; ++d)
                h[d] = fmaf(g[c], W[c * CG + q * 16 + d], h[d]);
        }
#pragma unroll
        for (int d = 0; d < 16; ++d) {
            hmax[d] = fmaxf(hmax[d], h[d]);
            hmin[d] = fminf(hmin[d], h[d]);
        }
    }
    // BN + ReLU + max-pool fused: max_k relu(s*h+t) = relu(s*(s>=0?hmax:hmin)+t)
#pragma unroll
    for (int d = 0; d < 16; ++d) {
        int ch = q * 16 + d;
        float s = bnp[ch] * rsqrtf(bnp[192 + ch] + EPS);
        float t = bnp[64 + ch] - bnp[128 + ch] * s;
        float hh = (s >= 0.f) ? hmax[d] : hmin[d];
        out16[d] = fmaxf(0.f, fmaf(s, hh, t));
    }
}

__global__ __launch_bounds__(256, 2)
void bignn_fused(const float* __restrict__ feat_s1, const float* __restrict__ feat_s2,
                 const float* __restrict__ feat_last,
                 const float* __restrict__ Wg1, const float* __restrict__ bn_g1,
                 const float* __restrict__ Wg2, const float* __restrict__ bn_g2,
                 const float* __restrict__ Wout, const float* __restrict__ bn_out,
                 const int* __restrict__ idx_s1, const int* __restrict__ idx_s2,
                 float* __restrict__ out)
{
    // p1|p2 per row; stride 129 floats -> bank = (r + j) % 32: conflict-free
    __shared__ float lds_p[ROWS_PER_BLOCK][129];

    const int r = threadIdx.x & 63;
    const int q = __builtin_amdgcn_readfirstlane(threadIdx.x >> 6);
    const int row  = blockIdx.x * ROWS_PER_BLOCK + r;
    const int rowc = row < N_ROWS ? row : N_ROWS - 1;

    float p1c[16], p2c[16];
    grouper_chunk<C1>(feat_s1, idx_s1, Wg1, bn_g1, rowc, q, p1c);
    grouper_chunk<C2>(feat_s2, idx_s2, Wg2, bn_g2, rowc, q, p2c);

#pragma unroll
    for (int d = 0; d < 16; ++d) {
        lds_p[r][q * 16 + d]      = p1c[d];
        lds_p[r][64 + q * 16 + d] = p2c[d];
    }
    __syncthreads();

    float acc[16];
#pragma unroll
    for (int d = 0; d < 16; ++d) acc[d] = 0.f;

    // feat_last contribution (rows 0..63 of Wout)
    const float4* flp = reinterpret_cast<const float4*>(feat_last + (size_t)rowc * CL);
#pragma unroll
    for (int j4 = 0; j4 < CL / 4; ++j4) {
        float4 v = flp[j4];
        float vv[4] = { v.x, v.y, v.z, v.w };
#pragma unroll
        for (int jj = 0; jj < 4; ++jj)
#pragma unroll
            for (int d = 0; d < 16; ++d)
                acc[d] = fmaf(vv[jj], Wout[(j4 * 4 + jj) * CG + q * 16 + d], acc[d]);
    }
    // p1|p2 contribution (rows 64..191 of Wout) read back from LDS
#pragma unroll 8
    for (int j = 0; j < 128; ++j) {
        float pv = lds_p[r][j];
#pragma unroll
        for (int d = 0; d < 16; ++d)
            acc[d] = fmaf(pv, Wout[(64 + j) * CG + q * 16 + d], acc[d]);
    }

    if (row < N_ROWS) {
#pragma unroll
        for (int d = 0; d < 16; ++d) {
            int ch = q * 16 + d;
            float s = bn_out[ch] * rsqrtf(bn_out[192 + ch] + EPS);
            float t = bn_out[64 + ch] - bn_out[128 + ch] * s;
            acc[d] = fmaxf(0.f, fmaf(s, acc[d], t));
        }
        float4* op = reinterpret_cast<float4*>(out + (size_t)row * CG + q * 16);
#pragma unroll
        for (int d4 = 0; d4 < 4; ++d4)
            op[d4] = make_float4(acc[4*d4+0], acc[4*d4+1], acc[4*d4+2], acc[4*d4+3]);
    }
}

extern "C" void kernel_launch(void* const* d_in, const int* in_sizes, int n_in,
                              void* d_out, int out_size, void* d_ws, size_t ws_size,
                              hipStream_t stream) {
    const float* feat_s1   = (const float*)d_in[0];
    const float* feat_s2   = (const float*)d_in[1];
    const float* feat_last = (const float*)d_in[2];
    const float* Wg1       = (const float*)d_in[3];
    const float* bn_g1     = (const float*)d_in[4];
    const float* Wg2       = (const float*)d_in[5];
    const float* bn_g2     = (const float*)d_in[6];
    const float* Wout      = (const float*)d_in[7];
    const float* bn_out    = (const float*)d_in[8];
    const int*   idx_s1    = (const int*)d_in[9];
    const int*   idx_s2    = (const int*)d_in[10];
    float* out = (float*)d_out;

    dim3 grid((N_ROWS + ROWS_PER_BLOCK - 1) / ROWS_PER_BLOCK);
    bignn_fused<<<grid, dim3(256), 0, stream>>>(
        feat_s1, feat_s2, feat_last, Wg1, bn_g1, Wg2, bn_g2, Wout, bn_out,
        idx_s1, idx_s2, out);
}

// Round 3
// 74.430 us; speedup vs baseline: 5.8649x; 5.8649x over previous
//
#include <hip/hip_runtime.h>

// BiGNN fused MFMA kernel (bf16 matmuls, f32 accumulate).
// Per block: 64 output rows, 4 waves, 16 rows/wave.
// Grouper: per output row, M = 16 neighbors, gather A-frags directly from
// global to registers (lane l = neighbor l&15, channels (l>>4)*8..+7), W^T
// B-frags register-resident (staged via LDS bf16). BN+ReLU+maxpool fused on
// the accumulator via sign-select + shfl_xor reduce. Final 192->64 layer is a
// 16-row MFMA GEMM with p1|p2 read back from LDS as bf16.

typedef __attribute__((ext_vector_type(8))) short short8;
typedef __attribute__((ext_vector_type(4))) float f32x4;

constexpr int N_ROWS = 50000;
constexpr int C1 = 32, C2 = 64, CL = 64, CG = 64;
constexpr float EPS = 1e-3f;
constexpr int RPB = 64, RPW = 16;

// ---- LDS layout (bytes) ----
constexpr int P_STRIDE = 136;                         // shorts/row: 128 + 8 pad (272B, 16B-aligned, 2-way max)
constexpr int P_BYTES  = 64 * P_STRIDE * 2;           // 17408
constexpr int ST_OFF   = P_BYTES;                     // 3 BNs x 64 x float2 = 1536
constexpr int UN_OFF   = ST_OFF + 3 * 64 * 8;         // 18944
// phase A union members:
constexpr int IDX1_OFF = UN_OFF;                      // [64][16] int = 4096
constexpr int IDX2_OFF = IDX1_OFF + 4096;             // 4096
constexpr int W1_STRIDE = 40;                         // shorts (80B rows)
constexpr int W2_STRIDE = 72;                         // shorts (144B rows)
constexpr int W1_OFF   = IDX2_OFF + 4096;             // 64*40*2 = 5120
constexpr int W2_OFF   = W1_OFF + 64 * W1_STRIDE * 2; // 64*72*2 = 9216 (ends 41472)
// phase B union member:
constexpr int WO_STRIDE = 200;                        // shorts (400B rows)
constexpr int WO_OFF   = UN_OFF;                      // 64*200*2 = 25600
constexpr int SMEM_BYTES = UN_OFF + 64 * WO_STRIDE * 2;  // 44544 -> 3 blocks/CU
static_assert(W2_OFF + 64 * W2_STRIDE * 2 <= SMEM_BYTES, "phase A fits");

__device__ __forceinline__ short f2bf(float f) {   // RNE via integer bit-trick
    unsigned u = __builtin_bit_cast(unsigned, f);
    unsigned r = u + 0x7fff + ((u >> 16) & 1);
    return (short)(r >> 16);
}
__device__ __forceinline__ short8 pack8(float4 x, float4 y) {
    short8 r;
    r[0] = f2bf(x.x); r[1] = f2bf(x.y); r[2] = f2bf(x.z); r[3] = f2bf(x.w);
    r[4] = f2bf(y.x); r[5] = f2bf(y.y); r[6] = f2bf(y.z); r[7] = f2bf(y.w);
    return r;
}
#define MFMA(a, b, c) __builtin_amdgcn_mfma_f32_16x16x32_bf16((a), (b), (c), 0, 0, 0)

__global__ __launch_bounds__(256, 3)
void bignn_mfma(const float* __restrict__ feat_s1, const float* __restrict__ feat_s2,
                const float* __restrict__ feat_last,
                const float* __restrict__ Wg1, const float* __restrict__ bn_g1,
                const float* __restrict__ Wg2, const float* __restrict__ bn_g2,
                const float* __restrict__ Wout, const float* __restrict__ bn_out,
                const int* __restrict__ idx_s1, const int* __restrict__ idx_s2,
                float* __restrict__ out)
{
    __shared__ __align__(16) char smem[SMEM_BYTES];
    short* p_lds  = (short*)smem;                       // [64][P_STRIDE]
    float2* st    = (float2*)(smem + ST_OFF);           // [3][64] (s, t)
    int*   idx1_l = (int*)(smem + IDX1_OFF);            // [64][16]
    int*   idx2_l = (int*)(smem + IDX2_OFF);
    short* w1t    = (short*)(smem + W1_OFF);            // [64][40]  (WT: [out_ch][c])
    short* w2t    = (short*)(smem + W2_OFF);            // [64][72]
    short* wot    = (short*)(smem + WO_OFF);            // [64][200] (phase B)

    const int t    = threadIdx.x;
    const int lane = t & 63, lc = lane & 15, hi = lane >> 4;
    const int wave = t >> 6;
    const int row0 = blockIdx.x * RPB;

    // ---------------- phase A staging ----------------
    {   // neighbor indices: 64 rows x 16, int4 per thread
        int r = t >> 2, j = (t & 3) * 4;
        int grow = min(row0 + r, N_ROWS - 1);
        *(int4*)(idx1_l + r * 16 + j) = *(const int4*)(idx_s1 + (size_t)grow * 16 + j);
        *(int4*)(idx2_l + r * 16 + j) = *(const int4*)(idx_s2 + (size_t)grow * 16 + j);
    }
    for (int e = t; e < C1 * CG; e += 256) {            // Wg1^T bf16
        int c = e >> 6, d = e & 63;
        w1t[d * W1_STRIDE + c] = f2bf(Wg1[e]);
    }
    for (int e = t; e < C2 * CG; e += 256) {            // Wg2^T bf16
        int c = e >> 6, d = e & 63;
        w2t[d * W2_STRIDE + c] = f2bf(Wg2[e]);
    }
    if (t < 192) {                                      // BN (s, t) per channel
        int which = t >> 6, ch = t & 63;
        const float* bnp = which == 0 ? bn_g1 : which == 1 ? bn_g2 : bn_out;
        float g = bnp[ch], b = bnp[64 + ch], m = bnp[128 + ch], v = bnp[192 + ch];
        float s = g * rsqrtf(v + EPS);
        st[which * 64 + ch] = make_float2(s, fmaf(-m, s, b));
    }
    __syncthreads();

    // B-frags for groupers, register-resident (reused 16x per wave)
    short8 bW1[4], bW2[2][4];
#pragma unroll
    for (int nt = 0; nt < 4; ++nt)
        bW1[nt] = *(const short8*)(w1t + (nt * 16 + lc) * W1_STRIDE + hi * 8);
#pragma unroll
    for (int ck = 0; ck < 2; ++ck)
#pragma unroll
        for (int nt = 0; nt < 4; ++nt)
            bW2[ck][nt] = *(const short8*)(w2t + (nt * 16 + lc) * W2_STRIDE + ck * 32 + hi * 8);

    // ---------------- grouper phase: 16 rows per wave ----------------
#pragma unroll 2
    for (int rr = 0; rr < RPW; ++rr) {
        const int r = wave * RPW + rr;                  // local row
        const int nb1 = idx1_l[r * 16 + lc];
        const int nb2 = idx2_l[r * 16 + lc];
        // gather A-frags straight to registers
        const float4* g1p = (const float4*)(feat_s1 + (size_t)nb1 * C1 + hi * 8);
        float4 a0 = g1p[0], a1 = g1p[1];
        const float4* g2p = (const float4*)(feat_s2 + (size_t)nb2 * C2 + hi * 8);
        float4 b0 = g2p[0], b1 = g2p[1];
        const float4* g2q = (const float4*)(feat_s2 + (size_t)nb2 * C2 + 32 + hi * 8);
        float4 c0 = g2q[0], c1 = g2q[1];

        f32x4 z = {0.f, 0.f, 0.f, 0.f};
        // grouper1: K=32, 4 N-tiles
        short8 af1 = pack8(a0, a1);
        f32x4 acc1[4];
#pragma unroll
        for (int nt = 0; nt < 4; ++nt) acc1[nt] = MFMA(af1, bW1[nt], z);
        // grouper2: K=64 (2 chunks), 4 N-tiles
        short8 af2a = pack8(b0, b1), af2b = pack8(c0, c1);
        f32x4 acc2[4];
#pragma unroll
        for (int nt = 0; nt < 4; ++nt) acc2[nt] = MFMA(af2a, bW2[0][nt], z);
#pragma unroll
        for (int nt = 0; nt < 4; ++nt) acc2[nt] = MFMA(af2b, bW2[1][nt], acc2[nt]);

        // fused BN+ReLU+maxpool: max_k relu(s*h+t) = relu(|s| * max_k(sgn(s)*h) + t)
        float pv1[4], pv2[4];
#pragma unroll
        for (int nt = 0; nt < 4; ++nt) {
            float2 s1 = st[0 * 64 + nt * 16 + lc];
            f32x4 a = acc1[nt];
            float m0 = s1.x >= 0.f ? a[0] : -a[0];
            float m1 = s1.x >= 0.f ? a[1] : -a[1];
            float m2 = s1.x >= 0.f ? a[2] : -a[2];
            float m3 = s1.x >= 0.f ? a[3] : -a[3];
            float m = fmaxf(fmaxf(m0, m1), fmaxf(m2, m3));
            m = fmaxf(m, __shfl_xor(m, 16));
            m = fmaxf(m, __shfl_xor(m, 32));
            pv1[nt] = fmaxf(0.f, fmaf(fabsf(s1.x), m, s1.y));

            float2 s2 = st[1 * 64 + nt * 16 + lc];
            f32x4 bacc = acc2[nt];
            float n0 = s2.x >= 0.f ? bacc[0] : -bacc[0];
            float n1 = s2.x >= 0.f ? bacc[1] : -bacc[1];
            float n2 = s2.x >= 0.f ? bacc[2] : -bacc[2];
            float n3 = s2.x >= 0.f ? bacc[3] : -bacc[3];
            float n = fmaxf(fmaxf(n0, n1), fmaxf(n2, n3));
            n = fmaxf(n, __shfl_xor(n, 16));
            n = fmaxf(n, __shfl_xor(n, 32));
            pv2[nt] = fmaxf(0.f, fmaf(fabsf(s2.x), n, s2.y));
        }
        // every lane holds all 4 nt values (broadcast after reduce); group hi writes nt==hi
        float w1v = hi == 0 ? pv1[0] : hi == 1 ? pv1[1] : hi == 2 ? pv1[2] : pv1[3];
        float w2v = hi == 0 ? pv2[0] : hi == 1 ? pv2[1] : hi == 2 ? pv2[2] : pv2[3];
        p_lds[r * P_STRIDE + hi * 16 + lc]       = f2bf(w1v);
        p_lds[r * P_STRIDE + 64 + hi * 16 + lc]  = f2bf(w2v);
    }
    __syncthreads();

    // ---------------- stage Wout^T bf16 (phase B union) ----------------
    for (int e = t; e < (CL + 2 * CG) * CG; e += 256) {  // 192*64
        int c = e >> 6, d = e & 63;
        wot[d * WO_STRIDE + c] = f2bf(Wout[e]);
    }
    __syncthreads();

    // ---------------- final layer: 16-row M-tile per wave ----------------
    const int tile0 = row0 + wave * RPW;
    {
        const int mrow = min(tile0 + lc, N_ROWS - 1);
        const float4* flp = (const float4*)(feat_last + (size_t)mrow * CL + hi * 8);
        float4 f0 = flp[0], f1 = flp[1];
        const float4* flq = (const float4*)(feat_last + (size_t)mrow * CL + 32 + hi * 8);
        float4 f2 = flq[0], f3 = flq[1];
        short8 aA = pack8(f0, f1), aB = pack8(f2, f3);

        f32x4 facc[4] = {{0.f,0.f,0.f,0.f},{0.f,0.f,0.f,0.f},{0.f,0.f,0.f,0.f},{0.f,0.f,0.f,0.f}};
#pragma unroll
        for (int ck = 0; ck < 6; ++ck) {
            short8 af;
            if (ck == 0) af = aA;
            else if (ck == 1) af = aB;
            else af = *(const short8*)(p_lds + (wave * RPW + lc) * P_STRIDE + (ck - 2) * 32 + hi * 8);
#pragma unroll
            for (int nt = 0; nt < 4; ++nt) {
                short8 bf = *(const short8*)(wot + (nt * 16 + lc) * WO_STRIDE + ck * 32 + hi * 8);
                facc[nt] = MFMA(af, bf, facc[nt]);
            }
        }
#pragma unroll
        for (int nt = 0; nt < 4; ++nt) {
            float2 so = st[2 * 64 + nt * 16 + lc];
#pragma unroll
            for (int rg = 0; rg < 4; ++rg) {
                int grow = tile0 + hi * 4 + rg;
                if (grow < N_ROWS) {
                    float v = fmaxf(0.f, fmaf(so.x, facc[nt][rg], so.y));
                    out[(size_t)grow * CG + nt * 16 + lc] = v;
                }
            }
        }
    }
}

extern "C" void kernel_launch(void* const* d_in, const int* in_sizes, int n_in,
                              void* d_out, int out_size, void* d_ws, size_t ws_size,
                              hipStream_t stream) {
    const float* feat_s1   = (const float*)d_in[0];
    const float* feat_s2   = (const float*)d_in[1];
    const float* feat_last = (const float*)d_in[2];
    const float* Wg1       = (const float*)d_in[3];
    const float* bn_g1     = (const float*)d_in[4];
    const float* Wg2       = (const float*)d_in[5];
    const float* bn_g2     = (const float*)d_in[6];
    const float* Wout      = (const float*)d_in[7];
    const float* bn_out    = (const float*)d_in[8];
    const int*   idx_s1    = (const int*)d_in[9];
    const int*   idx_s2    = (const int*)d_in[10];
    float* out = (float*)d_out;

    dim3 grid((N_ROWS + RPB - 1) / RPB);
    bignn_mfma<<<grid, dim3(256), 0, stream>>>(
        feat_s1, feat_s2, feat_last, Wg1, bn_g1, Wg2, bn_g2, Wout, bn_out,
        idx_s1, idx_s2, out);
}